// Round 3
// baseline (3924.417 us; speedup 1.0000x reference)
//
#include <hip/hip_runtime.h>
#include <hip/hip_fp16.h>

// 2-layer LSTM, B=256 T=512 I=32 H=256.
// 16 groups x 16 batches; 16 wgs/group x 128 thr (wave0: L0-slice, wave1: L1-slice).
// Each wave: 16 units x 4 gates, weights register-resident; all 4 gates in-register
// -> elementwise fully in-register (no Gbuf), ONE __syncthreads per phase.
// Cross-wg h exchange via sc0/sc1 (MALL-coherent) stores/loads; per-WAVE 1-byte
// monotone (mod-256) flags, coalesced 32B poll. ws = 512KB h slots + 512B flags.

#define NGRP  16
#define GB    16
#define WPG   16
#define NTH   128
#define HH    256
#define TT    512
#define II    32

typedef _Float16 f16x8 __attribute__((ext_vector_type(8)));
typedef float    f32x4 __attribute__((ext_vector_type(4)));

__device__ __forceinline__ f16x8 cvt8(const float* p) {
  const float4 a = *(const float4*)p;
  const float4 b = *(const float4*)(p + 4);
  f16x8 r;
  r[0]=(_Float16)a.x; r[1]=(_Float16)a.y; r[2]=(_Float16)a.z; r[3]=(_Float16)a.w;
  r[4]=(_Float16)b.x; r[5]=(_Float16)b.y; r[6]=(_Float16)b.z; r[7]=(_Float16)b.w;
  return r;
}

__device__ __forceinline__ float sigm(float x){ return 1.f/(1.f + __expf(-x)); }
__device__ __forceinline__ float tanh_(float x){ return 1.f - 2.f/(1.f + __expf(2.f*x)); }

// ---- MALL-coherent (L2-bypass) primitives ----
__device__ __forceinline__ uint4 load16_sc(const void* p) {
  uint4 r;
  asm volatile("global_load_dwordx4 %0, %1, off sc0 sc1"
               : "=v"(r) : "v"(p) : "memory");
  return r;
}
__device__ __forceinline__ void store2_sc(void* p, unsigned v) {
  asm volatile("global_store_short %0, %1, off sc0 sc1"
               :: "v"(p), "v"(v) : "memory");
}
__device__ __forceinline__ void store1_sc(void* p, unsigned v) {
  asm volatile("global_store_byte %0, %1, off sc0 sc1"
               :: "v"(p), "v"(v) : "memory");
}
__device__ __forceinline__ unsigned load1_sc(const void* p) {
  unsigned r;
  asm volatile("global_load_ubyte %0, %1, off sc0 sc1\n\ts_waitcnt vmcnt(0)"
               : "=v"(r) : "v"(p) : "memory");
  return r;
}

__global__ void zero_ws(uint4* p, int n) {
  int i = blockIdx.x * blockDim.x + threadIdx.x;
  if (i < n) p[i] = make_uint4(0u,0u,0u,0u);
}

__global__ __launch_bounds__(NTH, 1) void lstm_kernel(
    const float* __restrict__ M,
    const float* __restrict__ Wih0, const float* __restrict__ Whh0,
    const float* __restrict__ bih0, const float* __restrict__ bhh0,
    const float* __restrict__ Wih1, const float* __restrict__ Whh1,
    const float* __restrict__ bih1, const float* __restrict__ bhh1,
    float* __restrict__ out, char* __restrict__ ws)
{
  __shared__ __align__(16) char h0l[2][GB * 512];   // 8KB each, XOR-swizzled rows
  __shared__ __align__(16) char h1l[2][GB * 512];

  const int tid   = threadIdx.x;
  const int lane  = tid & 63;
  const int wv    = tid >> 6;            // 0: L0 slice, 1: L1 slice
  const int g     = blockIdx.x >> 4;     // group 0..15
  const int w     = blockIdx.x & 15;     // slice 0..15
  const bool isL1 = (wv == 1);
  const int col16 = lane & 15;
  const int ko8   = (lane >> 4) << 3;    // k-offset elems (0,8,16,24)
  const int unit  = w * 16 + col16;

  char* h0g = ws;                        // [2 slot][16 g][16 b][256 u] fp16 = 256KB
  char* h1g = ws + 262144;
  unsigned char* flags = (unsigned char*)(ws + 524288);  // [16 g][32 wave] u8 mod-256

  // ---- register-resident weights: 4 gates x 16 units ----
  f16x8 WA[4][8], WB[4][8], WI[4];
  float bias[4];
  #pragma unroll
  for (int q = 0; q < 4; ++q) {
    const int grow = q * HH + unit;
    if (!isL1) {
      #pragma unroll
      for (int kt = 0; kt < 8; ++kt)
        WA[q][kt] = cvt8(Whh0 + (size_t)grow * HH + kt * 32 + ko8);
      WI[q]   = cvt8(Wih0 + grow * II + ko8);
      bias[q] = bih0[grow] + bhh0[grow];
    } else {
      #pragma unroll
      for (int kt = 0; kt < 8; ++kt) {
        WA[q][kt] = cvt8(Wih1 + (size_t)grow * HH + kt * 32 + ko8);
        WB[q][kt] = cvt8(Whh1 + (size_t)grow * HH + kt * 32 + ko8);
      }
      bias[q] = bih1[grow] + bhh1[grow];
    }
  }

  // M[t=0] prefetch (L0 A-fragment is per-lane direct)
  float4 mA = {0,0,0,0}, mB = {0,0,0,0};
  if (!isL1) {
    const float* mp = M + ((size_t)(g * GB + col16) * TT + 0) * II + ko8;
    mA = *(const float4*)mp; mB = *(const float4*)(mp + 4);
  }

  float c[4] = {0.f, 0.f, 0.f, 0.f};
  const unsigned char* myflags = flags + g * 32;

  for (int p = 0; p <= TT; ++p) {
    // ---- poll: all 32 waves of this group completed phase p-1 ----
    if (p >= 1) {
      const unsigned char tgtb = (unsigned char)p;   // completed-count mod 256
      const unsigned char* fp_ = myflags + (lane & 31);
      while (true) {
        unsigned fb = load1_sc(fp_);
        int ok = ((int)(signed char)((unsigned char)fb - tgtb)) >= 0;
        if (__all(ok)) break;
      }
    }

    // ---- stage h0[p-1], h1[p-2] (16KB) into LDS par=p&1 ----
    const int rdslot = (p + 1) & 1;
    const char* s0 = h0g + rdslot * 131072 + g * 8192;
    const char* s1 = h1g + rdslot * 131072 + g * 8192;
    uint4 v[8];
    #pragma unroll
    for (int i = 0; i < 4; ++i) {
      v[i]     = load16_sc(s0 + ((i * NTH + tid) << 4));
      v[4 + i] = load16_sc(s1 + ((i * NTH + tid) << 4));
    }
    asm volatile("s_waitcnt vmcnt(0)" ::: "memory");
    __builtin_amdgcn_sched_barrier(0);
    const int par = p & 1;
    #pragma unroll
    for (int i = 0; i < 4; ++i) {
      const int ch  = i * NTH + tid;         // 16B chunk 0..511
      const int row = ch >> 5, ci = ch & 31;
      const int boff = (row << 9) + ((ci << 4) ^ ((row & 7) << 4));
      *(uint4*)(h0l[par] + boff) = v[i];
      *(uint4*)(h1l[par] + boff) = v[4 + i];
    }
    __syncthreads();

    // ---- MFMA: all 4 gates, A-frag shared across gates ----
    f32x4 acc[4];
    #pragma unroll
    for (int q = 0; q < 4; ++q) acc[q] = (f32x4){bias[q], bias[q], bias[q], bias[q]};

    if (!isL1) {
      if (p < TT) {
        f16x8 am;
        am[0]=(_Float16)mA.x; am[1]=(_Float16)mA.y; am[2]=(_Float16)mA.z; am[3]=(_Float16)mA.w;
        am[4]=(_Float16)mB.x; am[5]=(_Float16)mB.y; am[6]=(_Float16)mB.z; am[7]=(_Float16)mB.w;
        #pragma unroll
        for (int q = 0; q < 4; ++q)
          acc[q] = __builtin_amdgcn_mfma_f32_16x16x32_f16(am, WI[q], acc[q], 0, 0, 0);
        #pragma unroll
        for (int kt = 0; kt < 8; ++kt) {
          const int boff = (col16 << 9) + ((kt * 64 + (ko8 << 1)) ^ ((col16 & 7) << 4));
          f16x8 a = *(const f16x8*)(h0l[par] + boff);
          #pragma unroll
          for (int q = 0; q < 4; ++q)
            acc[q] = __builtin_amdgcn_mfma_f32_16x16x32_f16(a, WA[q][kt], acc[q], 0, 0, 0);
        }
      }
    } else if (p >= 1) {
      #pragma unroll
      for (int kt = 0; kt < 8; ++kt) {
        const int boff = (col16 << 9) + ((kt * 64 + (ko8 << 1)) ^ ((col16 & 7) << 4));
        f16x8 a = *(const f16x8*)(h0l[par] + boff);
        #pragma unroll
        for (int q = 0; q < 4; ++q)
          acc[q] = __builtin_amdgcn_mfma_f32_16x16x32_f16(a, WA[q][kt], acc[q], 0, 0, 0);
      }
      #pragma unroll
      for (int kt = 0; kt < 8; ++kt) {
        const int boff = (col16 << 9) + ((kt * 64 + (ko8 << 1)) ^ ((col16 & 7) << 4));
        f16x8 a = *(const f16x8*)(h1l[par] + boff);
        #pragma unroll
        for (int q = 0; q < 4; ++q)
          acc[q] = __builtin_amdgcn_mfma_f32_16x16x32_f16(a, WB[q][kt], acc[q], 0, 0, 0);
      }
    }

    // ---- elementwise fully in-register + sc h stores ----
    const int wrbase = par * 131072 + g * 8192;
    if (!isL1) {
      if (p < TT) {
        #pragma unroll
        for (int r = 0; r < 4; ++r) {
          const float iv = sigm(acc[0][r]), fv = sigm(acc[1][r]);
          const float gv = tanh_(acc[2][r]), ov = sigm(acc[3][r]);
          c[r] = fv * c[r] + iv * gv;
          const float h = ov * tanh_(c[r]);
          const int b = ((lane >> 4) << 2) + r;
          unsigned short hb = __builtin_bit_cast(unsigned short, (_Float16)h);
          store2_sc(h0g + wrbase + (b << 9) + (unit << 1), (unsigned)hb);
        }
      }
    } else if (p >= 1) {
      #pragma unroll
      for (int r = 0; r < 4; ++r) {
        const float iv = sigm(acc[0][r]), fv = sigm(acc[1][r]);
        const float gv = tanh_(acc[2][r]), ov = sigm(acc[3][r]);
        c[r] = fv * c[r] + iv * gv;
        const float h = ov * tanh_(c[r]);
        const int b = ((lane >> 4) << 2) + r;
        if (p < TT) {
          unsigned short hb = __builtin_bit_cast(unsigned short, (_Float16)h);
          store2_sc(h1g + wrbase + (b << 9) + (unit << 1), (unsigned)hb);
        } else {
          out[(size_t)(g * GB + b) * HH + unit] = h;   // final h1[T-1], fp32
        }
      }
    }

    // ---- per-wave completion flag (drain own stores first) ----
    if (p < TT) {
      asm volatile("s_waitcnt vmcnt(0)" ::: "memory");
      if (lane == 0)
        store1_sc((void*)(myflags + w * 2 + wv), (unsigned)((p + 1) & 0xFF));
      // M prefetch for next phase (after drain so it doesn't serialize it)
      if (!isL1 && p + 1 < TT) {
        const float* mp = M + ((size_t)(g * GB + col16) * TT + (p + 1)) * II + ko8;
        mA = *(const float4*)mp; mB = *(const float4*)(mp + 4);
      }
    }
  }
}

extern "C" void kernel_launch(void* const* d_in, const int* in_sizes, int n_in,
                              void* d_out, int out_size, void* d_ws, size_t ws_size,
                              hipStream_t stream) {
  (void)in_sizes; (void)n_in; (void)out_size;
  if (ws_size < 524800) return;   // 512KB h slots + 512B flags

  const float* M    = (const float*)d_in[0];
  const float* Wih0 = (const float*)d_in[1];
  const float* Whh0 = (const float*)d_in[2];
  const float* bih0 = (const float*)d_in[3];
  const float* bhh0 = (const float*)d_in[4];
  const float* Wih1 = (const float*)d_in[5];
  const float* Whh1 = (const float*)d_in[6];
  const float* bih1 = (const float*)d_in[7];
  const float* bhh1 = (const float*)d_in[8];

  const int nz = 32800;            // 524800 / 16
  zero_ws<<<(nz + 255) / 256, 256, 0, stream>>>((uint4*)d_ws, nz);
  lstm_kernel<<<NGRP * WPG, NTH, 0, stream>>>(M, Wih0, Whh0, bih0, bhh0,
                                              Wih1, Whh1, bih1, bhh1,
                                              (float*)d_out, (char*)d_ws);
}